// Round 7
// baseline (456.744 us; speedup 1.0000x reference)
//
#include <hip/hip_runtime.h>
#include <stdint.h>

#define S_ 2048
#define D_ 128
#define KBLK 32            // k-tile rows (main kernel)
#define NT 64              // k-tiles per bh
#define PST 40             // per-wave P row stride (shorts): 32 cols + 8 pad
#define TILE_SHORTS 4096   // 32*128
#define BUF_BYTES (32u * 64u * 8192u)  // 16 MiB per packed buffer

typedef __attribute__((ext_vector_type(8))) short bf16x8;
typedef __attribute__((ext_vector_type(4))) float f32x4;

__device__ __forceinline__ f32x4 mfma_bf(bf16x8 a, bf16x8 b, f32x4 c) {
  return __builtin_amdgcn_mfma_f32_16x16x32_bf16(a, b, c, 0, 0, 0);
}

__device__ __forceinline__ uint32_t rotl32(uint32_t x, uint32_t r) {
  return (x << r) | (x >> (32u - r));
}

// JAX threefry2x32, key(42), partitionable scheme: bits(i) = x0^x1 of
// threefry(key, (0, i)).
__device__ __forceinline__ uint32_t threefry_bits(uint32_t gidx) {
  const uint32_t K1 = 42u, K2 = 0x1BD11BF0u;
  uint32_t x0 = 0u;
  uint32_t x1 = gidx + K1;
#define TFR4(a, b, c, d)                    \
  x0 += x1; x1 = rotl32(x1, a); x1 ^= x0;   \
  x0 += x1; x1 = rotl32(x1, b); x1 ^= x0;   \
  x0 += x1; x1 = rotl32(x1, c); x1 ^= x0;   \
  x0 += x1; x1 = rotl32(x1, d); x1 ^= x0;
  TFR4(13u, 15u, 26u, 6u)   x0 += K1; x1 += K2 + 1u;
  TFR4(17u, 29u, 16u, 24u)  x0 += K2; x1 += 2u;
  TFR4(13u, 15u, 26u, 6u)             x1 += K1 + 3u;
  TFR4(17u, 29u, 16u, 24u)  x0 += K1; x1 += K2 + 4u;
  TFR4(13u, 15u, 26u, 6u)   x0 += K2; x1 += 5u;
#undef TFR4
  return x0 ^ x1;
}

__device__ __forceinline__ unsigned short f2bf(float x) {  // RNE
  uint32_t u = __float_as_uint(x);
  u += 0x7fffu + ((u >> 16) & 1u);
  return (unsigned short)(u >> 16);
}
__device__ __forceinline__ float bf2f(unsigned short h) {
  return __uint_as_float(((uint32_t)h) << 16);
}

// async global->LDS, 16B per lane. LDS dest = wave-uniform base + lane*16.
__device__ __forceinline__ void gload16(const void* g, void* l) {
  __builtin_amdgcn_global_load_lds(
      (const __attribute__((address_space(1))) unsigned int*)g,
      (__attribute__((address_space(3))) unsigned int*)l, 16, 0, 0);
}

// ---------------- prepack (KBLK=32 tiles): K -> hi/lo bf16 (XOR-swizzled
// LDS image), V -> fragment-order bf16 (dt-XOR LDS image) ----------------
__global__ __launch_bounds__(256) void prepack_kernel(
    const float* __restrict__ K, const float* __restrict__ V,
    unsigned short* __restrict__ pKhi, unsigned short* __restrict__ pKlo,
    unsigned short* __restrict__ pVf) {
  const int blk = blockIdx.x;  // bh*NT + t
  const int bh = blk >> 6;
  const int t = blk & 63;
  const int tid = threadIdx.x;

  const float* Kp = K + ((size_t)bh * S_ + t * KBLK) * D_;
  const float* Vp = V + ((size_t)bh * S_ + t * KBLK) * D_;
  unsigned short* oKhi = pKhi + (size_t)blk * TILE_SHORTS;
  unsigned short* oKlo = pKlo + (size_t)blk * TILE_SHORTS;
  unsigned short* oVf = pVf + (size_t)blk * TILE_SHORTS;

#pragma unroll
  for (int rep = 0; rep < 4; ++rep) {
    int flat = tid + rep * 256;  // 0..1023
    int kk = flat >> 5;          // 0..31
    int c = flat & 31;
    float4 v4 = *(const float4*)(Kp + (size_t)kk * D_ + 4 * c);
    unsigned short h0 = f2bf(v4.x), h1 = f2bf(v4.y), h2 = f2bf(v4.z), h3 = f2bf(v4.w);
    ushort4 hi = {h0, h1, h2, h3};
    ushort4 lo = {f2bf(v4.x - bf2f(h0)), f2bf(v4.y - bf2f(h1)),
                  f2bf(v4.z - bf2f(h2)), f2bf(v4.w - bf2f(h3))};
    int idx = kk * 128 + ((4 * c) ^ (8 * (kk & 7)));
    *(ushort4*)&oKhi[idx] = hi;
    *(ushort4*)&oKlo[idx] = lo;
  }
  // V frag order: value V[g*8+j][dt*16+l15] at ((dt)*64 + (ll^ (dt&7)))*8 + j
  {
    int c = tid & 31;
    int rb = tid >> 5;  // 0..7
    int kk0 = 4 * rb;   // 0..28
    int gg = (kk0 >> 3) & 3;
    int s4 = kk0 & 7;
    const float* vbase = Vp + (size_t)kk0 * D_ + 4 * c;
    float av[4][4];
    *(float4*)av[0] = *(const float4*)(vbase);
    *(float4*)av[1] = *(const float4*)(vbase + D_);
    *(float4*)av[2] = *(const float4*)(vbase + 2 * D_);
    *(float4*)av[3] = *(const float4*)(vbase + 3 * D_);
    int dt = c >> 2;
#pragma unroll
    for (int i = 0; i < 4; ++i) {
      int d = 4 * c + i;
      int ll = 16 * gg + (d & 15);
      ushort4 wv = {f2bf(av[0][i]), f2bf(av[1][i]), f2bf(av[2][i]), f2bf(av[3][i])};
      *(ushort4*)&oVf[(dt * 64 + (ll ^ (dt & 7))) * 8 + s4] = wv;
    }
  }
}

// ---------------- main: 4 waves, QBLK=64, KBLK=32, packed staging ----------
__global__ __launch_bounds__(256) void fattn_packed(
    const float* __restrict__ Q, const unsigned short* __restrict__ pKhi,
    const unsigned short* __restrict__ pKlo, const unsigned short* __restrict__ pVf,
    float* __restrict__ O) {
  __shared__ __align__(16) unsigned short sKhi[KBLK * D_];  // 8 KB
  __shared__ __align__(16) unsigned short sKlo[KBLK * D_];  // 8 KB
  __shared__ __align__(16) unsigned short sV[KBLK * D_];    // 8 KB
  __shared__ __align__(16) unsigned short sP[4 * 16 * PST]; // 5 KB

  const int bid = blockIdx.x;  // 1024 blocks
  const int slot = bid >> 3;
  const int bh = (bid & 7) * 4 + (slot >> 5);  // XCD-chunked (bijective)
  const int qt = slot & 31;

  const int tid = threadIdx.x;
  const int w = tid >> 6;
  const int lane = tid & 63;
  const int g = lane >> 4;
  const int l15 = lane & 15;

  const int q0w = qt * 64 + w * 16;

  const float* Qp = Q + (size_t)bh * (S_ * D_);
  float* Op = O + (size_t)bh * (S_ * D_);
  const char* tKhi = (const char*)(pKhi + (size_t)bh * NT * TILE_SHORTS);
  const char* tKlo = (const char*)(pKlo + (size_t)bh * NT * TILE_SHORTS);
  const char* tVf = (const char*)(pVf + (size_t)bh * NT * TILE_SHORTS);

  // ---- Q fragments: A row = l15, k element (g,j) -> d = ds*32 + g*8 + j ----
  bf16x8 qhi[4], qlo[4];
  {
    const float* qrow = Qp + (size_t)(q0w + l15) * D_;
#pragma unroll
    for (int ds = 0; ds < 4; ++ds) {
#pragma unroll
      for (int h4 = 0; h4 < 2; ++h4) {
        float4 qv = *(const float4*)(qrow + ds * 32 + g * 8 + h4 * 4);
        float qa[4] = {qv.x, qv.y, qv.z, qv.w};
#pragma unroll
        for (int tt = 0; tt < 4; ++tt) {
          int j = h4 * 4 + tt;
          unsigned short hb = f2bf(qa[tt]);
          qhi[ds][j] = (short)hb;
          qlo[ds][j] = (short)f2bf(qa[tt] - bf2f(hb));
        }
      }
    }
  }

  float mrun[4], lrun[4];
  f32x4 accO[8];
#pragma unroll
  for (int r = 0; r < 4; ++r) { mrun[r] = -1e30f; lrun[r] = 0.0f; }
#pragma unroll
  for (int dt = 0; dt < 8; ++dt) { f32x4 z = {0.f, 0.f, 0.f, 0.f}; accO[dt] = z; }

  uint32_t rowbase[4];
#pragma unroll
  for (int r = 0; r < 4; ++r)
    rowbase[r] = (uint32_t)(bh * S_ + q0w + g * 4 + r) * (uint32_t)S_;

  unsigned short* sPw = sP + w * (16 * PST);

  for (int kt = 0; kt < NT; ++kt) {
    __syncthreads();  // prior iter's LDS readers done before restage

    // ---- stage K hi/lo + V via global_load_lds (pre-swizzled images) ----
    {
      size_t tb = (size_t)kt * 8192;  // tile bytes
#pragma unroll
      for (int i = 0; i < 2; ++i) {
        int co = (w * 2 + i) * 1024;  // chunk byte offset, wave-uniform
        int bo = co + lane * 16;
        gload16(tKhi + tb + bo, ((char*)sKhi) + co);
        gload16(tKlo + tb + bo, ((char*)sKlo) + co);
        gload16(tVf + tb + bo, ((char*)sV) + co);
      }
    }
    __syncthreads();  // drains vmcnt before any wave reads

    // ---- S = Q K^T, hi/lo 3-product, swizzled reads ----
    f32x4 sfr[2];
#pragma unroll
    for (int ct = 0; ct < 2; ++ct) {
      f32x4 acc = {0.f, 0.f, 0.f, 0.f};
      int kcol = ct * 16 + l15;
      int rbse = kcol * 128;
      int sw = 8 * (kcol & 7);
#pragma unroll
      for (int ds = 0; ds < 4; ++ds) {
        int off = rbse + ((32 * ds + 8 * g) ^ sw);
        bf16x8 kh = *(const bf16x8*)&sKhi[off];
        bf16x8 kl = *(const bf16x8*)&sKlo[off];
        acc = mfma_bf(qhi[ds], kh, acc);
        acc = mfma_bf(qhi[ds], kl, acc);
        acc = mfma_bf(qlo[ds], kh, acc);
      }
      sfr[ct] = acc;  // lane: S[q0w + g*4 + r][kt*32 + ct*16 + l15]
    }

    // ---- deferred-max online softmax (THR=8; p <= e^8 safe) ----
    float tmax[4];
    int anyup = 0;
#pragma unroll
    for (int r = 0; r < 4; ++r) {
      float v = fmaxf(sfr[0][r], sfr[1][r]);
      v = fmaxf(v, __shfl_xor(v, 1));
      v = fmaxf(v, __shfl_xor(v, 2));
      v = fmaxf(v, __shfl_xor(v, 4));
      v = fmaxf(v, __shfl_xor(v, 8));
      tmax[r] = v;
      anyup |= (v > mrun[r] + 8.0f);
    }
    if (__any(anyup)) {
      float alpha[4];
#pragma unroll
      for (int r = 0; r < 4; ++r) {
        float nm = fmaxf(mrun[r], tmax[r]);
        alpha[r] = __expf(mrun[r] - nm);
        mrun[r] = nm;
        lrun[r] *= alpha[r];
      }
#pragma unroll
      for (int dt = 0; dt < 8; ++dt) {
#pragma unroll
        for (int r = 0; r < 4; ++r) accO[dt][r] *= alpha[r];
      }
    }

    // ---- p + dropout; full cluster skip (exp+psum+hash) when negligible ----
#pragma unroll
    for (int ct = 0; ct < 2; ++ct) {
      uint32_t kglob = (uint32_t)(kt * KBLK + ct * 16 + l15);
#pragma unroll
      for (int r = 0; r < 4; ++r) {
        float e = sfr[ct][r] - mrun[r];
        unsigned short pds = 0;
        if (__any(e > -10.0f)) {  // wave-uniform branch
          float p = __expf(e);
          lrun[r] += p;  // per-lane partial; reduced once in epilogue
          uint32_t bits = threefry_bits(rowbase[r] + kglob);
          float u = __uint_as_float((bits >> 9) | 0x3f800000u) - 1.0f;
          pds = f2bf((u < 0.9f) ? p : 0.0f);
        }
        sPw[(g * 4 + r) * PST + ct * 16 + l15] = pds;
      }
    }

    asm volatile("s_waitcnt lgkmcnt(0)" ::: "memory");
    __builtin_amdgcn_sched_barrier(0);
    bf16x8 pa0 = *(const bf16x8*)&sPw[l15 * PST + 8 * g];
    asm volatile("s_waitcnt lgkmcnt(0)" ::: "memory");  // read done pre-overwrite
    __builtin_amdgcn_sched_barrier(0);

    // ---- O += P V ----
#pragma unroll
    for (int dt = 0; dt < 8; ++dt) {
      bf16x8 vb = *(const bf16x8*)&sV[(dt * 64 + (lane ^ (dt & 7))) * 8];
      accO[dt] = mfma_bf(pa0, vb, accO[dt]);
    }
  }

  // ---- epilogue: reduce lrun across the 16-lane group, then O / (0.9*l) ----
#pragma unroll
  for (int r = 0; r < 4; ++r) {
    float v = lrun[r];
    v += __shfl_xor(v, 1);
    v += __shfl_xor(v, 2);
    v += __shfl_xor(v, 4);
    v += __shfl_xor(v, 8);
    float inv = 1.0f / (0.9f * v);
    float* orow = Op + (size_t)(q0w + g * 4 + r) * D_ + l15;
#pragma unroll
    for (int dt = 0; dt < 8; ++dt) orow[dt * 16] = accO[dt][r] * inv;
  }
}

// ---------------- fallback (R4, proven, KBLK=64) if ws too small ----------
__global__ __launch_bounds__(256) void fattn_fallback(
    const float* __restrict__ Q, const float* __restrict__ K,
    const float* __restrict__ V, float* __restrict__ O) {
  __shared__ __align__(16) unsigned short sKhi[64 * D_];
  __shared__ __align__(16) unsigned short sKlo[64 * D_];
  __shared__ __align__(16) unsigned short sV[64 * D_];
  __shared__ __align__(16) unsigned short sP[4 * 16 * 40];

  const int bid = blockIdx.x;
  const int slot = bid >> 3;
  const int bh = (bid & 7) * 4 + (slot >> 5);
  const int qt = slot & 31;
  const int tid = threadIdx.x;
  const int w = tid >> 6;
  const int lane = tid & 63;
  const int g = lane >> 4;
  const int l15 = lane & 15;
  const int q0w = qt * 64 + w * 16;

  const float* Qp = Q + (size_t)bh * (S_ * D_);
  const float* Kp = K + (size_t)bh * (S_ * D_);
  const float* Vp = V + (size_t)bh * (S_ * D_);
  float* Op = O + (size_t)bh * (S_ * D_);

  bf16x8 qhi[4], qlo[4];
  {
    const float* qrow = Qp + (size_t)(q0w + l15) * D_;
#pragma unroll
    for (int ds = 0; ds < 4; ++ds) {
#pragma unroll
      for (int h4 = 0; h4 < 2; ++h4) {
        float4 qv = *(const float4*)(qrow + ds * 32 + g * 8 + h4 * 4);
        float qa[4] = {qv.x, qv.y, qv.z, qv.w};
#pragma unroll
        for (int tt = 0; tt < 4; ++tt) {
          int j = h4 * 4 + tt;
          unsigned short hb = f2bf(qa[tt]);
          qhi[ds][j] = (short)hb;
          qlo[ds][j] = (short)f2bf(qa[tt] - bf2f(hb));
        }
      }
    }
  }

  float mrun[4], lrun[4];
  f32x4 accO[8];
#pragma unroll
  for (int r = 0; r < 4; ++r) { mrun[r] = -1e30f; lrun[r] = 0.0f; }
#pragma unroll
  for (int dt = 0; dt < 8; ++dt) { f32x4 z = {0.f, 0.f, 0.f, 0.f}; accO[dt] = z; }

  uint32_t rowbase[4];
#pragma unroll
  for (int r = 0; r < 4; ++r)
    rowbase[r] = (uint32_t)(bh * S_ + q0w + g * 4 + r) * (uint32_t)S_;

  unsigned short* sPw = sP + w * (16 * 40);

  for (int kt = 0; kt < S_; kt += 64) {
    __syncthreads();
#pragma unroll
    for (int rep = 0; rep < 8; ++rep) {
      int flat = tid + rep * 256;
      int kk = flat >> 5;
      int c = flat & 31;
      float4 v4 = *(const float4*)(Kp + (size_t)(kt + kk) * D_ + 4 * c);
      unsigned short h0 = f2bf(v4.x), h1 = f2bf(v4.y), h2 = f2bf(v4.z), h3 = f2bf(v4.w);
      ushort4 hi = {h0, h1, h2, h3};
      ushort4 lo = {f2bf(v4.x - bf2f(h0)), f2bf(v4.y - bf2f(h1)),
                    f2bf(v4.z - bf2f(h2)), f2bf(v4.w - bf2f(h3))};
      int idx = kk * 128 + ((4 * c) ^ (8 * (kk & 7)));
      *(ushort4*)&sKhi[idx] = hi;
      *(ushort4*)&sKlo[idx] = lo;
    }
#pragma unroll
    for (int rep = 0; rep < 2; ++rep) {
      int c = tid & 31;
      int rb = (tid >> 5) + 8 * rep;
      int kk0 = 4 * rb;
      int ks = kk0 >> 5;
      int gg = (kk0 >> 3) & 3;
      int s4 = kk0 & 7;
      const float* vbase = Vp + (size_t)(kt + kk0) * D_ + 4 * c;
      float av[4][4];
      *(float4*)av[0] = *(const float4*)(vbase);
      *(float4*)av[1] = *(const float4*)(vbase + D_);
      *(float4*)av[2] = *(const float4*)(vbase + 2 * D_);
      *(float4*)av[3] = *(const float4*)(vbase + 3 * D_);
      int dt = c >> 2;
#pragma unroll
      for (int i = 0; i < 4; ++i) {
        int d = 4 * c + i;
        int ll = 16 * gg + (d & 15);
        ushort4 wv = {f2bf(av[0][i]), f2bf(av[1][i]), f2bf(av[2][i]), f2bf(av[3][i])};
        *(ushort4*)&sV[((ks * 8 + dt) * 64 + (ll ^ (dt & 7))) * 8 + s4] = wv;
      }
    }
    __syncthreads();

    f32x4 sfr[4];
#pragma unroll
    for (int ct = 0; ct < 4; ++ct) {
      f32x4 acc = {0.f, 0.f, 0.f, 0.f};
      int kcol = ct * 16 + l15;
      int rbse = kcol * 128;
      int sw = 8 * (kcol & 7);
#pragma unroll
      for (int ds = 0; ds < 4; ++ds) {
        int off = rbse + ((32 * ds + 8 * g) ^ sw);
        bf16x8 kh = *(const bf16x8*)&sKhi[off];
        bf16x8 kl = *(const bf16x8*)&sKlo[off];
        acc = mfma_bf(qhi[ds], kh, acc);
        acc = mfma_bf(qhi[ds], kl, acc);
        acc = mfma_bf(qlo[ds], kh, acc);
      }
      sfr[ct] = acc;
    }

    float alpha[4];
#pragma unroll
    for (int r = 0; r < 4; ++r) {
      float v = fmaxf(fmaxf(sfr[0][r], sfr[1][r]), fmaxf(sfr[2][r], sfr[3][r]));
      v = fmaxf(v, __shfl_xor(v, 1));
      v = fmaxf(v, __shfl_xor(v, 2));
      v = fmaxf(v, __shfl_xor(v, 4));
      v = fmaxf(v, __shfl_xor(v, 8));
      float nm = fmaxf(mrun[r], v);
      alpha[r] = __expf(mrun[r] - nm);
      mrun[r] = nm;
      lrun[r] *= alpha[r];
    }
#pragma unroll
    for (int dt = 0; dt < 8; ++dt) {
#pragma unroll
      for (int r = 0; r < 4; ++r) accO[dt][r] *= alpha[r];
    }

    float psum[4] = {0.f, 0.f, 0.f, 0.f};
    bf16x8 pa0, pa1;
#pragma unroll
    for (int half = 0; half < 2; ++half) {
#pragma unroll
      for (int ct2 = 0; ct2 < 2; ++ct2) {
        int ct = half * 2 + ct2;
        uint32_t kglob = (uint32_t)(kt + ct * 16 + l15);
#pragma unroll
        for (int r = 0; r < 4; ++r) {
          float p = __expf(sfr[ct][r] - mrun[r]);
          psum[r] += p;
          uint32_t bits = threefry_bits(rowbase[r] + kglob);
          float u = __uint_as_float((bits >> 9) | 0x3f800000u) - 1.0f;
          float pd = (u < 0.9f) ? p : 0.0f;
          sPw[(g * 4 + r) * 40 + ct2 * 16 + l15] = f2bf(pd);
        }
      }
      asm volatile("s_waitcnt lgkmcnt(0)" ::: "memory");
      __builtin_amdgcn_sched_barrier(0);
      if (half == 0) pa0 = *(const bf16x8*)&sPw[l15 * 40 + 8 * g];
      else           pa1 = *(const bf16x8*)&sPw[l15 * 40 + 8 * g];
      asm volatile("s_waitcnt lgkmcnt(0)" ::: "memory");
      __builtin_amdgcn_sched_barrier(0);
    }
#pragma unroll
    for (int r = 0; r < 4; ++r) {
      float v = psum[r];
      v += __shfl_xor(v, 1);
      v += __shfl_xor(v, 2);
      v += __shfl_xor(v, 4);
      v += __shfl_xor(v, 8);
      lrun[r] += v;
    }

#pragma unroll
    for (int dt = 0; dt < 8; ++dt) {
      bf16x8 vb0 = *(const bf16x8*)&sV[((0 * 8 + dt) * 64 + (lane ^ (dt & 7))) * 8];
      accO[dt] = mfma_bf(pa0, vb0, accO[dt]);
      bf16x8 vb1 = *(const bf16x8*)&sV[((1 * 8 + dt) * 64 + (lane ^ (dt & 7))) * 8];
      accO[dt] = mfma_bf(pa1, vb1, accO[dt]);
    }
  }

#pragma unroll
  for (int r = 0; r < 4; ++r) {
    float inv = 1.0f / (0.9f * lrun[r]);
    float* orow = Op + (size_t)(q0w + g * 4 + r) * D_ + l15;
#pragma unroll
    for (int dt = 0; dt < 8; ++dt) orow[dt * 16] = accO[dt][r] * inv;
  }
}

extern "C" void kernel_launch(void* const* d_in, const int* in_sizes, int n_in,
                              void* d_out, int out_size, void* d_ws, size_t ws_size,
                              hipStream_t stream) {
  (void)in_sizes; (void)n_in; (void)out_size;
  const float* Q = (const float*)d_in[0];
  const float* K = (const float*)d_in[1];
  const float* V = (const float*)d_in[2];
  float* O = (float*)d_out;

  if (ws_size >= (size_t)3 * BUF_BYTES) {
    unsigned short* pKhi = (unsigned short*)d_ws;
    unsigned short* pKlo = (unsigned short*)((char*)d_ws + BUF_BYTES);
    unsigned short* pVf = (unsigned short*)((char*)d_ws + 2 * (size_t)BUF_BYTES);
    prepack_kernel<<<dim3(2048), dim3(256), 0, stream>>>(K, V, pKhi, pKlo, pVf);
    fattn_packed<<<dim3(1024), dim3(256), 0, stream>>>(Q, pKhi, pKlo, pVf, O);
  } else {
    fattn_fallback<<<dim3(1024), dim3(256), 0, stream>>>(Q, K, V, O);
  }
}

// Round 8
// 399.865 us; speedup vs baseline: 1.1422x; 1.1422x over previous
//
#include <hip/hip_runtime.h>
#include <stdint.h>

#define S_ 2048
#define D_ 128
#define KBLK 64
#define NT 32              // k-tiles per bh
#define PSTRIDE 40         // fallback per-wave P row stride (shorts)
#define PST 72             // main per-wave P row stride (shorts): 64 cols + 8 pad
#define TILE_SHORTS 8192   // 64*128
#define BUF_BYTES (32u * 32u * 16384u)  // 16 MiB per packed buffer
// keep ⟺ (bits>>9) < 0x733333 ⟺ bits < 0x733333<<9  (exactly u<0.9f)
#define KEEP_THR 0xE6666600u

typedef __attribute__((ext_vector_type(8))) short bf16x8;
typedef __attribute__((ext_vector_type(4))) float f32x4;

__device__ __forceinline__ f32x4 mfma_bf(bf16x8 a, bf16x8 b, f32x4 c) {
  return __builtin_amdgcn_mfma_f32_16x16x32_bf16(a, b, c, 0, 0, 0);
}

// JAX threefry2x32, key(42), partitionable scheme: bits(i) = x0^x1 of
// threefry(key, (0, i)). Rotates via fshl -> v_alignbit_b32 (1 op).
__device__ __forceinline__ uint32_t threefry_bits(uint32_t gidx) {
  const uint32_t K1 = 42u, K2 = 0x1BD11BF0u;
  uint32_t x0 = 0u;
  uint32_t x1 = gidx + K1;
#define TFR4(a, b, c, d)                                      \
  x0 += x1; x1 = __builtin_rotateleft32(x1, a); x1 ^= x0;     \
  x0 += x1; x1 = __builtin_rotateleft32(x1, b); x1 ^= x0;     \
  x0 += x1; x1 = __builtin_rotateleft32(x1, c); x1 ^= x0;     \
  x0 += x1; x1 = __builtin_rotateleft32(x1, d); x1 ^= x0;
  TFR4(13u, 15u, 26u, 6u)   x0 += K1; x1 += K2 + 1u;
  TFR4(17u, 29u, 16u, 24u)  x0 += K2; x1 += 2u;
  TFR4(13u, 15u, 26u, 6u)             x1 += K1 + 3u;
  TFR4(17u, 29u, 16u, 24u)  x0 += K1; x1 += K2 + 4u;
  TFR4(13u, 15u, 26u, 6u)   x0 += K2; x1 += 5u;
#undef TFR4
  return x0 ^ x1;
}

__device__ __forceinline__ unsigned short f2bf(float x) {  // RNE
  uint32_t u = __float_as_uint(x);
  u += 0x7fffu + ((u >> 16) & 1u);
  return (unsigned short)(u >> 16);
}
__device__ __forceinline__ float bf2f(unsigned short h) {
  return __uint_as_float(((uint32_t)h) << 16);
}

// async global->LDS, 16B per lane. LDS dest = wave-uniform base + lane*16.
__device__ __forceinline__ void gload16(const void* g, void* l) {
  __builtin_amdgcn_global_load_lds(
      (const __attribute__((address_space(1))) unsigned int*)g,
      (__attribute__((address_space(3))) unsigned int*)l, 16, 0, 0);
}

// ---------------- prepack: K -> hi/lo bf16 (XOR-swizzled LDS image),
//                  V -> fragment-order bf16 (dt-XOR LDS image) ----------------
__global__ __launch_bounds__(256) void prepack_kernel(
    const float* __restrict__ K, const float* __restrict__ V,
    unsigned short* __restrict__ pKhi, unsigned short* __restrict__ pKlo,
    unsigned short* __restrict__ pVf) {
  const int blk = blockIdx.x;  // bh*NT + t
  const int bh = blk >> 5;
  const int t = blk & 31;
  const int tid = threadIdx.x;

  const float* Kp = K + ((size_t)bh * S_ + t * KBLK) * D_;
  const float* Vp = V + ((size_t)bh * S_ + t * KBLK) * D_;
  unsigned short* oKhi = pKhi + (size_t)blk * TILE_SHORTS;
  unsigned short* oKlo = pKlo + (size_t)blk * TILE_SHORTS;
  unsigned short* oVf = pVf + (size_t)blk * TILE_SHORTS;

#pragma unroll
  for (int rep = 0; rep < 8; ++rep) {
    int flat = tid + rep * 256;
    int kk = flat >> 5;
    int c = flat & 31;
    float4 v4 = *(const float4*)(Kp + (size_t)kk * D_ + 4 * c);
    unsigned short h0 = f2bf(v4.x), h1 = f2bf(v4.y), h2 = f2bf(v4.z), h3 = f2bf(v4.w);
    ushort4 hi = {h0, h1, h2, h3};
    ushort4 lo = {f2bf(v4.x - bf2f(h0)), f2bf(v4.y - bf2f(h1)),
                  f2bf(v4.z - bf2f(h2)), f2bf(v4.w - bf2f(h3))};
    int idx = kk * 128 + ((4 * c) ^ (8 * (kk & 7)));
    *(ushort4*)&oKhi[idx] = hi;
    *(ushort4*)&oKlo[idx] = lo;
  }
#pragma unroll
  for (int rep = 0; rep < 2; ++rep) {
    int c = tid & 31;
    int rb = (tid >> 5) + 8 * rep;  // 0..15
    int kk0 = 4 * rb;
    int ks = kk0 >> 5;
    int gg = (kk0 >> 3) & 3;
    int s4 = kk0 & 7;
    const float* vbase = Vp + (size_t)kk0 * D_ + 4 * c;
    float av[4][4];
    *(float4*)av[0] = *(const float4*)(vbase);
    *(float4*)av[1] = *(const float4*)(vbase + D_);
    *(float4*)av[2] = *(const float4*)(vbase + 2 * D_);
    *(float4*)av[3] = *(const float4*)(vbase + 3 * D_);
    int dt = c >> 2;
#pragma unroll
    for (int i = 0; i < 4; ++i) {
      int d = 4 * c + i;
      int ll = 16 * gg + (d & 15);
      ushort4 wv = {f2bf(av[0][i]), f2bf(av[1][i]), f2bf(av[2][i]), f2bf(av[3][i])};
      *(ushort4*)&oVf[((ks * 8 + dt) * 64 + (ll ^ (dt & 7))) * 8 + s4] = wv;
    }
  }
}

// ---------------- main: 8 waves, QBLK=128, packed staging ----------------
__global__ __launch_bounds__(512) void fattn_packed(
    const float* __restrict__ Q, const unsigned short* __restrict__ pKhi,
    const unsigned short* __restrict__ pKlo, const unsigned short* __restrict__ pVf,
    float* __restrict__ O) {
  __shared__ __align__(16) unsigned short sKhi[KBLK * D_];
  __shared__ __align__(16) unsigned short sKlo[KBLK * D_];
  __shared__ __align__(16) unsigned short sV[KBLK * D_];
  __shared__ __align__(16) unsigned short sP[8 * 16 * PST];

  const int bid = blockIdx.x;  // 512 blocks
  const int xcd = bid & 7;
  const int slot = bid >> 3;                 // 0..63
  const int bh = xcd * 4 + (slot >> 4);      // 0..31, XCD-chunked (bijective)
  const int qt = slot & 15;                  // q-tile of 128 rows

  const int tid = threadIdx.x;
  const int w = tid >> 6;    // 0..7
  const int lane = tid & 63;
  const int g = lane >> 4;
  const int l15 = lane & 15;

  const int q0w = qt * 128 + w * 16;

  const float* Qp = Q + (size_t)bh * (S_ * D_);
  float* Op = O + (size_t)bh * (S_ * D_);
  const char* tKhi = (const char*)(pKhi + (size_t)bh * NT * TILE_SHORTS);
  const char* tKlo = (const char*)(pKlo + (size_t)bh * NT * TILE_SHORTS);
  const char* tVf = (const char*)(pVf + (size_t)bh * NT * TILE_SHORTS);

  // ---- Q fragments: A row = l15, k element (g,j) -> d = ds*32 + g*8 + j ----
  bf16x8 qhi[4], qlo[4];
  {
    const float* qrow = Qp + (size_t)(q0w + l15) * D_;
#pragma unroll
    for (int ds = 0; ds < 4; ++ds) {
#pragma unroll
      for (int h4 = 0; h4 < 2; ++h4) {
        float4 qv = *(const float4*)(qrow + ds * 32 + g * 8 + h4 * 4);
        float qa[4] = {qv.x, qv.y, qv.z, qv.w};
#pragma unroll
        for (int tt = 0; tt < 4; ++tt) {
          int j = h4 * 4 + tt;
          unsigned short hb = f2bf(qa[tt]);
          qhi[ds][j] = (short)hb;
          qlo[ds][j] = (short)f2bf(qa[tt] - bf2f(hb));
        }
      }
    }
  }

  float mrun[4], lrun[4];
  f32x4 accO[8];
#pragma unroll
  for (int r = 0; r < 4; ++r) { mrun[r] = -1e30f; lrun[r] = 0.0f; }
#pragma unroll
  for (int dt = 0; dt < 8; ++dt) { f32x4 z = {0.f, 0.f, 0.f, 0.f}; accO[dt] = z; }

  uint32_t rowbase[4];
#pragma unroll
  for (int r = 0; r < 4; ++r)
    rowbase[r] = (uint32_t)(bh * S_ + q0w + g * 4 + r) * (uint32_t)S_;

  unsigned short* sPw = sP + w * (16 * PST);

  for (int kt = 0; kt < NT; ++kt) {
    __syncthreads();  // prior iter's LDS readers done before restage

    // ---- stage K hi/lo + V via global_load_lds (pre-swizzled images) ----
    {
      size_t tb = (size_t)kt * 16384;
#pragma unroll
      for (int i = 0; i < 2; ++i) {
        int co = (w * 2 + i) * 1024;  // chunk byte offset, wave-uniform
        int bo = co + lane * 16;
        gload16(tKhi + tb + bo, ((char*)sKhi) + co);
        gload16(tKlo + tb + bo, ((char*)sKlo) + co);
        gload16(tVf + tb + bo, ((char*)sV) + co);
      }
    }
    __syncthreads();  // drains vmcnt before any wave reads

    // ---- S = Q K^T, hi/lo 3-product, swizzled reads ----
    f32x4 sfr[4];
#pragma unroll
    for (int ct = 0; ct < 4; ++ct) {
      f32x4 acc = {0.f, 0.f, 0.f, 0.f};
      int kcol = ct * 16 + l15;
      int rbse = kcol * 128;
      int sw = 8 * (kcol & 7);
#pragma unroll
      for (int ds = 0; ds < 4; ++ds) {
        int off = rbse + ((32 * ds + 8 * g) ^ sw);
        bf16x8 kh = *(const bf16x8*)&sKhi[off];
        bf16x8 kl = *(const bf16x8*)&sKlo[off];
        acc = mfma_bf(qhi[ds], kh, acc);
        acc = mfma_bf(qhi[ds], kl, acc);
        acc = mfma_bf(qlo[ds], kh, acc);
      }
      sfr[ct] = acc;  // lane: S[q0w + g*4 + r][kt*64 + ct*16 + l15]
    }

    // ---- deferred-max online softmax (THR=8; p <= e^8 safe) ----
    float tmax[4];
    int anyup = 0;
#pragma unroll
    for (int r = 0; r < 4; ++r) {
      float v = fmaxf(fmaxf(sfr[0][r], sfr[1][r]), fmaxf(sfr[2][r], sfr[3][r]));
      v = fmaxf(v, __shfl_xor(v, 1));
      v = fmaxf(v, __shfl_xor(v, 2));
      v = fmaxf(v, __shfl_xor(v, 4));
      v = fmaxf(v, __shfl_xor(v, 8));
      tmax[r] = v;
      anyup |= (v > mrun[r] + 8.0f);
    }
    if (__any(anyup)) {
      float alpha[4];
#pragma unroll
      for (int r = 0; r < 4; ++r) {
        float nm = fmaxf(mrun[r], tmax[r]);
        alpha[r] = __expf(mrun[r] - nm);
        mrun[r] = nm;
        lrun[r] *= alpha[r];
      }
#pragma unroll
      for (int dt = 0; dt < 8; ++dt) {
#pragma unroll
        for (int r = 0; r < 4; ++r) accO[dt][r] *= alpha[r];
      }
    }

    // ---- p + dropout; full cluster skip (exp+psum+hash) when negligible ----
#pragma unroll
    for (int ct = 0; ct < 4; ++ct) {
      uint32_t kglob = (uint32_t)(kt * KBLK + ct * 16 + l15);
#pragma unroll
      for (int r = 0; r < 4; ++r) {
        float e = sfr[ct][r] - mrun[r];
        unsigned short pds = 0;
        if (__any(e > -10.0f)) {  // wave-uniform branch
          float p = __expf(e);
          lrun[r] += p;  // per-lane partial; reduced once in epilogue
          uint32_t bits = threefry_bits(rowbase[r] + kglob);
          pds = f2bf((bits < KEEP_THR) ? p : 0.0f);  // == (u < 0.9f), exact
        }
        sPw[(g * 4 + r) * PST + ct * 16 + l15] = pds;
      }
    }

    // single write->read fence; read-before-next-overwrite is ordered by the
    // loop-top __syncthreads (full LDS fence), so no second fence needed
    asm volatile("s_waitcnt lgkmcnt(0)" ::: "memory");
    __builtin_amdgcn_sched_barrier(0);
    bf16x8 pa0 = *(const bf16x8*)&sPw[l15 * PST + 8 * g];
    bf16x8 pa1 = *(const bf16x8*)&sPw[l15 * PST + 32 + 8 * g];

    // ---- O += P V ----
#pragma unroll
    for (int dt = 0; dt < 8; ++dt) {
      bf16x8 vb0 = *(const bf16x8*)&sV[((0 * 8 + dt) * 64 + (lane ^ (dt & 7))) * 8];
      accO[dt] = mfma_bf(pa0, vb0, accO[dt]);
      bf16x8 vb1 = *(const bf16x8*)&sV[((1 * 8 + dt) * 64 + (lane ^ (dt & 7))) * 8];
      accO[dt] = mfma_bf(pa1, vb1, accO[dt]);
    }
  }

  // ---- epilogue: reduce lrun across the 16-lane group, then O / (0.9*l) ----
#pragma unroll
  for (int r = 0; r < 4; ++r) {
    float v = lrun[r];
    v += __shfl_xor(v, 1);
    v += __shfl_xor(v, 2);
    v += __shfl_xor(v, 4);
    v += __shfl_xor(v, 8);
    float inv = 1.0f / (0.9f * v);
    float* orow = Op + (size_t)(q0w + g * 4 + r) * D_ + l15;
#pragma unroll
    for (int dt = 0; dt < 8; ++dt) orow[dt * 16] = accO[dt][r] * inv;
  }
}

// ---------------- fallback (R4, proven) if ws too small ----------------
__global__ __launch_bounds__(256) void fattn_fallback(
    const float* __restrict__ Q, const float* __restrict__ K,
    const float* __restrict__ V, float* __restrict__ O) {
  __shared__ __align__(16) unsigned short sKhi[KBLK * D_];
  __shared__ __align__(16) unsigned short sKlo[KBLK * D_];
  __shared__ __align__(16) unsigned short sV[KBLK * D_];
  __shared__ __align__(16) unsigned short sP[4 * 16 * PSTRIDE];

  const int bid = blockIdx.x;
  const int slot = bid >> 3;
  const int bh = (bid & 7) * 4 + (slot >> 5);
  const int qt = slot & 31;
  const int tid = threadIdx.x;
  const int w = tid >> 6;
  const int lane = tid & 63;
  const int g = lane >> 4;
  const int l15 = lane & 15;
  const int q0w = qt * 64 + w * 16;

  const float* Qp = Q + (size_t)bh * (S_ * D_);
  const float* Kp = K + (size_t)bh * (S_ * D_);
  const float* Vp = V + (size_t)bh * (S_ * D_);
  float* Op = O + (size_t)bh * (S_ * D_);

  bf16x8 qhi[4], qlo[4];
  {
    const float* qrow = Qp + (size_t)(q0w + l15) * D_;
#pragma unroll
    for (int ds = 0; ds < 4; ++ds) {
#pragma unroll
      for (int h4 = 0; h4 < 2; ++h4) {
        float4 qv = *(const float4*)(qrow + ds * 32 + g * 8 + h4 * 4);
        float qa[4] = {qv.x, qv.y, qv.z, qv.w};
#pragma unroll
        for (int tt = 0; tt < 4; ++tt) {
          int j = h4 * 4 + tt;
          unsigned short hb = f2bf(qa[tt]);
          qhi[ds][j] = (short)hb;
          qlo[ds][j] = (short)f2bf(qa[tt] - bf2f(hb));
        }
      }
    }
  }

  float mrun[4], lrun[4];
  f32x4 accO[8];
#pragma unroll
  for (int r = 0; r < 4; ++r) { mrun[r] = -1e30f; lrun[r] = 0.0f; }
#pragma unroll
  for (int dt = 0; dt < 8; ++dt) { f32x4 z = {0.f, 0.f, 0.f, 0.f}; accO[dt] = z; }

  uint32_t rowbase[4];
#pragma unroll
  for (int r = 0; r < 4; ++r)
    rowbase[r] = (uint32_t)(bh * S_ + q0w + g * 4 + r) * (uint32_t)S_;

  unsigned short* sPw = sP + w * (16 * PSTRIDE);

  for (int kt = 0; kt < S_; kt += KBLK) {
    __syncthreads();
#pragma unroll
    for (int rep = 0; rep < 8; ++rep) {
      int flat = tid + rep * 256;
      int kk = flat >> 5;
      int c = flat & 31;
      float4 v4 = *(const float4*)(Kp + (size_t)(kt + kk) * D_ + 4 * c);
      unsigned short h0 = f2bf(v4.x), h1 = f2bf(v4.y), h2 = f2bf(v4.z), h3 = f2bf(v4.w);
      ushort4 hi = {h0, h1, h2, h3};
      ushort4 lo = {f2bf(v4.x - bf2f(h0)), f2bf(v4.y - bf2f(h1)),
                    f2bf(v4.z - bf2f(h2)), f2bf(v4.w - bf2f(h3))};
      int idx = kk * 128 + ((4 * c) ^ (8 * (kk & 7)));
      *(ushort4*)&sKhi[idx] = hi;
      *(ushort4*)&sKlo[idx] = lo;
    }
#pragma unroll
    for (int rep = 0; rep < 2; ++rep) {
      int c = tid & 31;
      int rb = (tid >> 5) + 8 * rep;
      int kk0 = 4 * rb;
      int ks = kk0 >> 5;
      int gg = (kk0 >> 3) & 3;
      int s4 = kk0 & 7;
      const float* vbase = Vp + (size_t)(kt + kk0) * D_ + 4 * c;
      float av[4][4];
      *(float4*)av[0] = *(const float4*)(vbase);
      *(float4*)av[1] = *(const float4*)(vbase + D_);
      *(float4*)av[2] = *(const float4*)(vbase + 2 * D_);
      *(float4*)av[3] = *(const float4*)(vbase + 3 * D_);
      int dt = c >> 2;
#pragma unroll
      for (int i = 0; i < 4; ++i) {
        int d = 4 * c + i;
        int ll = 16 * gg + (d & 15);
        ushort4 wv = {f2bf(av[0][i]), f2bf(av[1][i]), f2bf(av[2][i]), f2bf(av[3][i])};
        *(ushort4*)&sV[((ks * 8 + dt) * 64 + (ll ^ (dt & 7))) * 8 + s4] = wv;
      }
    }
    __syncthreads();

    f32x4 sfr[4];
#pragma unroll
    for (int ct = 0; ct < 4; ++ct) {
      f32x4 acc = {0.f, 0.f, 0.f, 0.f};
      int kcol = ct * 16 + l15;
      int rbse = kcol * 128;
      int sw = 8 * (kcol & 7);
#pragma unroll
      for (int ds = 0; ds < 4; ++ds) {
        int off = rbse + ((32 * ds + 8 * g) ^ sw);
        bf16x8 kh = *(const bf16x8*)&sKhi[off];
        bf16x8 kl = *(const bf16x8*)&sKlo[off];
        acc = mfma_bf(qhi[ds], kh, acc);
        acc = mfma_bf(qhi[ds], kl, acc);
        acc = mfma_bf(qlo[ds], kh, acc);
      }
      sfr[ct] = acc;
    }

    float alpha[4];
#pragma unroll
    for (int r = 0; r < 4; ++r) {
      float v = fmaxf(fmaxf(sfr[0][r], sfr[1][r]), fmaxf(sfr[2][r], sfr[3][r]));
      v = fmaxf(v, __shfl_xor(v, 1));
      v = fmaxf(v, __shfl_xor(v, 2));
      v = fmaxf(v, __shfl_xor(v, 4));
      v = fmaxf(v, __shfl_xor(v, 8));
      float nm = fmaxf(mrun[r], v);
      alpha[r] = __expf(mrun[r] - nm);
      mrun[r] = nm;
      lrun[r] *= alpha[r];
    }
#pragma unroll
    for (int dt = 0; dt < 8; ++dt) {
#pragma unroll
      for (int r = 0; r < 4; ++r) accO[dt][r] *= alpha[r];
    }

    float psum[4] = {0.f, 0.f, 0.f, 0.f};
    bf16x8 pa0, pa1;
#pragma unroll
    for (int half = 0; half < 2; ++half) {
#pragma unroll
      for (int ct2 = 0; ct2 < 2; ++ct2) {
        int ct = half * 2 + ct2;
        uint32_t kglob = (uint32_t)(kt + ct * 16 + l15);
#pragma unroll
        for (int r = 0; r < 4; ++r) {
          float p = __expf(sfr[ct][r] - mrun[r]);
          psum[r] += p;
          uint32_t bits = threefry_bits(rowbase[r] + kglob);
          float pd = (bits < KEEP_THR) ? p : 0.0f;
          sPw[(g * 4 + r) * PSTRIDE + ct2 * 16 + l15] = f2bf(pd);
        }
      }
      asm volatile("s_waitcnt lgkmcnt(0)" ::: "memory");
      __builtin_amdgcn_sched_barrier(0);
      if (half == 0) pa0 = *(const bf16x8*)&sPw[l15 * PSTRIDE + 8 * g];
      else           pa1 = *(const bf16x8*)&sPw[l15 * PSTRIDE + 8 * g];
      asm volatile("s_waitcnt lgkmcnt(0)" ::: "memory");
      __builtin_amdgcn_sched_barrier(0);
    }
#pragma unroll
    for (int r = 0; r < 4; ++r) {
      float v = psum[r];
      v += __shfl_xor(v, 1);
      v += __shfl_xor(v, 2);
      v += __shfl_xor(v, 4);
      v += __shfl_xor(v, 8);
      lrun[r] += v;
    }

#pragma unroll
    for (int dt = 0; dt < 8; ++dt) {
      bf16x8 vb0 = *(const bf16x8*)&sV[((0 * 8 + dt) * 64 + (lane ^ (dt & 7))) * 8];
      accO[dt] = mfma_bf(pa0, vb0, accO[dt]);
      bf16x8 vb1 = *(const bf16x8*)&sV[((1 * 8 + dt) * 64 + (lane ^ (dt & 7))) * 8];
      accO[dt] = mfma_bf(pa1, vb1, accO[dt]);
    }
  }

#pragma unroll
  for (int r = 0; r < 4; ++r) {
    float inv = 1.0f / (0.9f * lrun[r]);
    float* orow = Op + (size_t)(q0w + g * 4 + r) * D_ + l15;
#pragma unroll
    for (int dt = 0; dt < 8; ++dt) orow[dt * 16] = accO[dt][r] * inv;
  }
}

extern "C" void kernel_launch(void* const* d_in, const int* in_sizes, int n_in,
                              void* d_out, int out_size, void* d_ws, size_t ws_size,
                              hipStream_t stream) {
  (void)in_sizes; (void)n_in; (void)out_size;
  const float* Q = (const float*)d_in[0];
  const float* K = (const float*)d_in[1];
  const float* V = (const float*)d_in[2];
  float* O = (float*)d_out;

  if (ws_size >= (size_t)3 * BUF_BYTES) {
    unsigned short* pKhi = (unsigned short*)d_ws;
    unsigned short* pKlo = (unsigned short*)((char*)d_ws + BUF_BYTES);
    unsigned short* pVf = (unsigned short*)((char*)d_ws + 2 * (size_t)BUF_BYTES);
    prepack_kernel<<<dim3(1024), dim3(256), 0, stream>>>(K, V, pKhi, pKlo, pVf);
    fattn_packed<<<dim3(512), dim3(512), 0, stream>>>(Q, pKhi, pKlo, pVf, O);
  } else {
    fattn_fallback<<<dim3(1024), dim3(256), 0, stream>>>(Q, K, V, O);
  }
}

// Round 10
// 314.202 us; speedup vs baseline: 1.4537x; 1.2726x over previous
//
#include <hip/hip_runtime.h>
#include <stdint.h>

#define S_ 2048
#define D_ 128
#define KBLK 64
#define NT 32              // k-tiles per bh
#define PSTRIDE 40         // fallback per-wave P row stride (shorts)
#define TILE_SHORTS 8192   // 64*128
#define BUF_BYTES (32u * 32u * 16384u)  // 16 MiB per packed buffer
// keep ⟺ (bits>>9) < 0x733333 ⟺ bits < 0x733333<<9  (exactly u<0.9f)
#define KEEP_THR 0xE6666600u

typedef __attribute__((ext_vector_type(8))) short bf16x8;
typedef __attribute__((ext_vector_type(4))) float f32x4;
typedef __attribute__((ext_vector_type(4))) uint32_t u32x4;

__device__ __forceinline__ f32x4 mfma_bf(bf16x8 a, bf16x8 b, f32x4 c) {
  return __builtin_amdgcn_mfma_f32_16x16x32_bf16(a, b, c, 0, 0, 0);
}

// JAX threefry2x32, key(42), partitionable scheme: bits(i) = x0^x1 of
// threefry(key, (0, i)).
__device__ __forceinline__ uint32_t threefry_bits(uint32_t gidx) {
  const uint32_t K1 = 42u, K2 = 0x1BD11BF0u;
  uint32_t x0 = 0u;
  uint32_t x1 = gidx + K1;
#define TFR4(a, b, c, d)                                      \
  x0 += x1; x1 = __builtin_rotateleft32(x1, a); x1 ^= x0;     \
  x0 += x1; x1 = __builtin_rotateleft32(x1, b); x1 ^= x0;     \
  x0 += x1; x1 = __builtin_rotateleft32(x1, c); x1 ^= x0;     \
  x0 += x1; x1 = __builtin_rotateleft32(x1, d); x1 ^= x0;
  TFR4(13u, 15u, 26u, 6u)   x0 += K1; x1 += K2 + 1u;
  TFR4(17u, 29u, 16u, 24u)  x0 += K2; x1 += 2u;
  TFR4(13u, 15u, 26u, 6u)             x1 += K1 + 3u;
  TFR4(17u, 29u, 16u, 24u)  x0 += K1; x1 += K2 + 4u;
  TFR4(13u, 15u, 26u, 6u)   x0 += K2; x1 += 5u;
#undef TFR4
  return x0 ^ x1;
}

__device__ __forceinline__ unsigned short f2bf(float x) {  // RNE
  uint32_t u = __float_as_uint(x);
  u += 0x7fffu + ((u >> 16) & 1u);
  return (unsigned short)(u >> 16);
}
__device__ __forceinline__ float bf2f(unsigned short h) {
  return __uint_as_float(((uint32_t)h) << 16);
}
__device__ __forceinline__ uint32_t cvtpk(float lo, float hi) {
  uint32_t r;
  asm("v_cvt_pk_bf16_f32 %0, %1, %2" : "=v"(r) : "v"(lo), "v"(hi));
  return r;
}

// async global->LDS, 16B per lane. LDS dest = wave-uniform base + lane*16.
__device__ __forceinline__ void gload16(const void* g, void* l) {
  __builtin_amdgcn_global_load_lds(
      (const __attribute__((address_space(1))) unsigned int*)g,
      (__attribute__((address_space(3))) unsigned int*)l, 16, 0, 0);
}

// ---------------- prepack: K -> hi/lo bf16 (XOR-swizzled LDS image),
//                  V -> fragment-order bf16 (dt-XOR LDS image) ----------------
__global__ __launch_bounds__(256) void prepack_kernel(
    const float* __restrict__ K, const float* __restrict__ V,
    unsigned short* __restrict__ pKhi, unsigned short* __restrict__ pKlo,
    unsigned short* __restrict__ pVf) {
  const int blk = blockIdx.x;  // bh*NT + t
  const int bh = blk >> 5;
  const int t = blk & 31;
  const int tid = threadIdx.x;

  const float* Kp = K + ((size_t)bh * S_ + t * KBLK) * D_;
  const float* Vp = V + ((size_t)bh * S_ + t * KBLK) * D_;
  unsigned short* oKhi = pKhi + (size_t)blk * TILE_SHORTS;
  unsigned short* oKlo = pKlo + (size_t)blk * TILE_SHORTS;
  unsigned short* oVf = pVf + (size_t)blk * TILE_SHORTS;

#pragma unroll
  for (int rep = 0; rep < 8; ++rep) {
    int flat = tid + rep * 256;
    int kk = flat >> 5;
    int c = flat & 31;
    float4 v4 = *(const float4*)(Kp + (size_t)kk * D_ + 4 * c);
    unsigned short h0 = f2bf(v4.x), h1 = f2bf(v4.y), h2 = f2bf(v4.z), h3 = f2bf(v4.w);
    ushort4 hi = {h0, h1, h2, h3};
    ushort4 lo = {f2bf(v4.x - bf2f(h0)), f2bf(v4.y - bf2f(h1)),
                  f2bf(v4.z - bf2f(h2)), f2bf(v4.w - bf2f(h3))};
    int idx = kk * 128 + ((4 * c) ^ (8 * (kk & 7)));
    *(ushort4*)&oKhi[idx] = hi;
    *(ushort4*)&oKlo[idx] = lo;
  }
#pragma unroll
  for (int rep = 0; rep < 2; ++rep) {
    int c = tid & 31;
    int rb = (tid >> 5) + 8 * rep;  // 0..15
    int kk0 = 4 * rb;
    int ks = kk0 >> 5;
    int gg = (kk0 >> 3) & 3;
    int s4 = kk0 & 7;
    const float* vbase = Vp + (size_t)kk0 * D_ + 4 * c;
    float av[4][4];
    *(float4*)av[0] = *(const float4*)(vbase);
    *(float4*)av[1] = *(const float4*)(vbase + D_);
    *(float4*)av[2] = *(const float4*)(vbase + 2 * D_);
    *(float4*)av[3] = *(const float4*)(vbase + 3 * D_);
    int dt = c >> 2;
#pragma unroll
    for (int i = 0; i < 4; ++i) {
      int d = 4 * c + i;
      int ll = 16 * gg + (d & 15);
      ushort4 wv = {f2bf(av[0][i]), f2bf(av[1][i]), f2bf(av[2][i]), f2bf(av[3][i])};
      *(ushort4*)&oVf[((ks * 8 + dt) * 64 + (ll ^ (dt & 7))) * 8 + s4] = wv;
    }
  }
}

// -------- main: 8 waves, QBLK=128, swapped QK^T, in-register P (no sP) ------
__global__ __launch_bounds__(512) void fattn_packed(
    const float* __restrict__ Q, const unsigned short* __restrict__ pKhi,
    const unsigned short* __restrict__ pKlo, const unsigned short* __restrict__ pVf,
    float* __restrict__ O) {
  __shared__ __align__(16) unsigned short sKhi[KBLK * D_];  // 16 KB
  __shared__ __align__(16) unsigned short sKlo[KBLK * D_];  // 16 KB
  __shared__ __align__(16) unsigned short sV[KBLK * D_];    // 16 KB (48 total)

  const int bid = blockIdx.x;  // 512 blocks
  const int xcd = bid & 7;
  const int slot = bid >> 3;                 // 0..63
  const int bh = xcd * 4 + (slot >> 4);      // 0..31, XCD-chunked (bijective)
  const int qt = slot & 15;                  // q-tile of 128 rows

  const int tid = threadIdx.x;
  const int w = tid >> 6;    // 0..7
  const int lane = tid & 63;
  const int g = lane >> 4;
  const int l15 = lane & 15;

  const int q0w = qt * 128 + w * 16;

  const float* Qp = Q + (size_t)bh * (S_ * D_);
  float* Op = O + (size_t)bh * (S_ * D_);
  const char* tKhi = (const char*)(pKhi + (size_t)bh * NT * TILE_SHORTS);
  const char* tKlo = (const char*)(pKlo + (size_t)bh * NT * TILE_SHORTS);
  const char* tVf = (const char*)(pVf + (size_t)bh * NT * TILE_SHORTS);

  // ---- Q fragments (B operand now): col = l15, k element (g,j) -> d ----
  bf16x8 qhi[4], qlo[4];
  {
    const float* qrow = Qp + (size_t)(q0w + l15) * D_;
#pragma unroll
    for (int ds = 0; ds < 4; ++ds) {
#pragma unroll
      for (int h4 = 0; h4 < 2; ++h4) {
        float4 qv = *(const float4*)(qrow + ds * 32 + g * 8 + h4 * 4);
        float qa[4] = {qv.x, qv.y, qv.z, qv.w};
#pragma unroll
        for (int tt = 0; tt < 4; ++tt) {
          int j = h4 * 4 + tt;
          unsigned short hb = f2bf(qa[tt]);
          qhi[ds][j] = (short)hb;
          qlo[ds][j] = (short)f2bf(qa[tt] - bf2f(hb));
        }
      }
    }
  }

  float mrun = -1e30f, lrun = 0.0f;  // for q-row = l15 (replicated across g)
  f32x4 accO[8];
#pragma unroll
  for (int dt = 0; dt < 8; ++dt) { f32x4 z = {0.f, 0.f, 0.f, 0.f}; accO[dt] = z; }

  const uint32_t rowbase = (uint32_t)(bh * S_ + q0w + l15) * (uint32_t)S_;

  for (int kt = 0; kt < NT; ++kt) {
    __syncthreads();  // prior iter's LDS readers done before restage

    // ---- stage K hi/lo + V via global_load_lds (pre-swizzled images) ----
    {
      size_t tb = (size_t)kt * 16384;
#pragma unroll
      for (int i = 0; i < 2; ++i) {
        int co = (w * 2 + i) * 1024;  // chunk byte offset, wave-uniform
        int bo = co + lane * 16;
        gload16(tKhi + tb + bo, ((char*)sKhi) + co);
        gload16(tKlo + tb + bo, ((char*)sKlo) + co);
        gload16(tVf + tb + bo, ((char*)sV) + co);
      }
    }
    __syncthreads();  // drains vmcnt before any wave reads

    // ---- S^T = K Q^T (swapped operands; same LDS reads, same Q frags) ----
    // lane (g,l15) reg r of sfr[ct]: S[q = l15][k = kt*64 + ct*16 + g*4 + r]
    f32x4 sfr[4];
#pragma unroll
    for (int ct = 0; ct < 4; ++ct) {
      f32x4 acc = {0.f, 0.f, 0.f, 0.f};
      int kcol = ct * 16 + l15;
      int rbse = kcol * 128;
      int sw = 8 * (kcol & 7);
#pragma unroll
      for (int ds = 0; ds < 4; ++ds) {
        int off = rbse + ((32 * ds + 8 * g) ^ sw);
        bf16x8 kh = *(const bf16x8*)&sKhi[off];
        bf16x8 kl = *(const bf16x8*)&sKlo[off];
        acc = mfma_bf(kh, qhi[ds], acc);
        acc = mfma_bf(kl, qhi[ds], acc);
        acc = mfma_bf(kh, qlo[ds], acc);
      }
      sfr[ct] = acc;
    }

    // ---- deferred-max online softmax (per-lane row q=l15) ----
    float v01 = fmaxf(fmaxf(sfr[0][0], sfr[0][1]), fmaxf(sfr[0][2], sfr[0][3]));
    float v23 = fmaxf(fmaxf(sfr[1][0], sfr[1][1]), fmaxf(sfr[1][2], sfr[1][3]));
    float v45 = fmaxf(fmaxf(sfr[2][0], sfr[2][1]), fmaxf(sfr[2][2], sfr[2][3]));
    float v67 = fmaxf(fmaxf(sfr[3][0], sfr[3][1]), fmaxf(sfr[3][2], sfr[3][3]));
    float vmax = fmaxf(fmaxf(v01, v23), fmaxf(v45, v67));
    vmax = fmaxf(vmax, __shfl_xor(vmax, 16));
    vmax = fmaxf(vmax, __shfl_xor(vmax, 32));
    if (__any(vmax > mrun + 8.0f)) {
      float nm = fmaxf(mrun, vmax);
      float alpha = __expf(mrun - nm);
      mrun = nm;
      lrun *= alpha;
      float ar[4];
#pragma unroll
      for (int r = 0; r < 4; ++r) ar[r] = __shfl(alpha, 4 * g + r);
#pragma unroll
      for (int dt = 0; dt < 8; ++dt) {
#pragma unroll
        for (int r = 0; r < 4; ++r) accO[dt][r] *= ar[r];
      }
    }

    // ---- p + dropout in place (cluster skip on wave-uniform __any) ----
#pragma unroll
    for (int ct = 0; ct < 4; ++ct) {
      uint32_t kb = (uint32_t)(kt * KBLK + ct * 16 + 4 * g);
#pragma unroll
      for (int r = 0; r < 4; ++r) {
        float e = sfr[ct][r] - mrun;
        float pv = 0.0f;
        if (__any(e > -10.0f)) {  // wave-uniform branch
          pv = __expf(e);
          lrun += pv;  // partial (this lane's 16 k); reduced in epilogue
          uint32_t bits = threefry_bits(rowbase + kb + r);
          if (bits >= KEEP_THR) pv = 0.0f;  // == !(u < 0.9f), exact
        }
        sfr[ct][r] = pv;
      }
    }

    // ---- in-register P exchange -> PV A-fragment (no LDS, no fence) ----
    // pk[ct][r2] packs (p[ct][2r2], p[ct][2r2+1]) as 2xbf16.
    uint32_t pk[4][2];
#pragma unroll
    for (int ct = 0; ct < 4; ++ct) {
      pk[ct][0] = cvtpk(sfr[ct][0], sfr[ct][1]);
      pk[ct][1] = cvtpk(sfr[ct][2], sfr[ct][3]);
    }
    // dest lane g=(g1,g0) word wj=(j2,r2) of ks-half:
    //   src lane = l15 + 16*((g0<<1)|j2), array idx ct_s = ks*2 + g1
    const int g1 = g >> 1, g0 = g & 1;
    u32x4 paw0, paw1;
#pragma unroll
    for (int wj = 0; wj < 4; ++wj) {
      int j2 = wj >> 1, r2 = wj & 1;
      int src = l15 + 16 * ((g0 << 1) | j2);
      uint32_t a0 = (uint32_t)__shfl((int)pk[0][r2], src);
      uint32_t b0 = (uint32_t)__shfl((int)pk[1][r2], src);
      paw0[wj] = g1 ? b0 : a0;
      uint32_t a1 = (uint32_t)__shfl((int)pk[2][r2], src);
      uint32_t b1 = (uint32_t)__shfl((int)pk[3][r2], src);
      paw1[wj] = g1 ? b1 : a1;
    }
    bf16x8 pa0 = __builtin_bit_cast(bf16x8, paw0);
    bf16x8 pa1 = __builtin_bit_cast(bf16x8, paw1);

    // ---- O += P V ----
#pragma unroll
    for (int dt = 0; dt < 8; ++dt) {
      bf16x8 vb0 = *(const bf16x8*)&sV[((0 * 8 + dt) * 64 + (lane ^ (dt & 7))) * 8];
      accO[dt] = mfma_bf(pa0, vb0, accO[dt]);
      bf16x8 vb1 = *(const bf16x8*)&sV[((1 * 8 + dt) * 64 + (lane ^ (dt & 7))) * 8];
      accO[dt] = mfma_bf(pa1, vb1, accO[dt]);
    }
  }

  // ---- epilogue: full row-sum, broadcast per accO row, O / (0.9*l) ----
  float ls = lrun;
  ls += __shfl_xor(ls, 16);
  ls += __shfl_xor(ls, 32);
#pragma unroll
  for (int r = 0; r < 4; ++r) {
    float lr = __shfl(ls, 4 * g + r);
    float inv = 1.0f / (0.9f * lr);
    float* orow = Op + (size_t)(q0w + 4 * g + r) * D_ + l15;
#pragma unroll
    for (int dt = 0; dt < 8; ++dt) orow[dt * 16] = accO[dt][r] * inv;
  }
}

// ---------------- fallback (R4-proven, 3-product) if ws too small ----------
__global__ __launch_bounds__(256) void fattn_fallback(
    const float* __restrict__ Q, const float* __restrict__ K,
    const float* __restrict__ V, float* __restrict__ O) {
  __shared__ __align__(16) unsigned short sKhi[KBLK * D_];
  __shared__ __align__(16) unsigned short sKlo[KBLK * D_];
  __shared__ __align__(16) unsigned short sV[KBLK * D_];
  __shared__ __align__(16) unsigned short sP[4 * 16 * PSTRIDE];

  const int bid = blockIdx.x;
  const int slot = bid >> 3;
  const int bh = (bid & 7) * 4 + (slot >> 5);
  const int qt = slot & 31;
  const int tid = threadIdx.x;
  const int w = tid >> 6;
  const int lane = tid & 63;
  const int g = lane >> 4;
  const int l15 = lane & 15;
  const int q0w = qt * 64 + w * 16;

  const float* Qp = Q + (size_t)bh * (S_ * D_);
  const float* Kp = K + (size_t)bh * (S_ * D_);
  const float* Vp = V + (size_t)bh * (S_ * D_);
  float* Op = O + (size_t)bh * (S_ * D_);

  bf16x8 qhi[4], qlo[4];
  {
    const float* qrow = Qp + (size_t)(q0w + l15) * D_;
#pragma unroll
    for (int ds = 0; ds < 4; ++ds) {
#pragma unroll
      for (int h4 = 0; h4 < 2; ++h4) {
        float4 qv = *(const float4*)(qrow + ds * 32 + g * 8 + h4 * 4);
        float qa[4] = {qv.x, qv.y, qv.z, qv.w};
#pragma unroll
        for (int tt = 0; tt < 4; ++tt) {
          int j = h4 * 4 + tt;
          unsigned short hb = f2bf(qa[tt]);
          qhi[ds][j] = (short)hb;
          qlo[ds][j] = (short)f2bf(qa[tt] - bf2f(hb));
        }
      }
    }
  }

  float mrun[4], lrun[4];
  f32x4 accO[8];
#pragma unroll
  for (int r = 0; r < 4; ++r) { mrun[r] = -1e30f; lrun[r] = 0.0f; }
#pragma unroll
  for (int dt = 0; dt < 8; ++dt) { f32x4 z = {0.f, 0.f, 0.f, 0.f}; accO[dt] = z; }

  uint32_t rowbase[4];
#pragma unroll
  for (int r = 0; r < 4; ++r)
    rowbase[r] = (uint32_t)(bh * S_ + q0w + g * 4 + r) * (uint32_t)S_;

  unsigned short* sPw = sP + w * (16 * PSTRIDE);

  for (int kt = 0; kt < S_; kt += KBLK) {
    __syncthreads();
#pragma unroll
    for (int rep = 0; rep < 8; ++rep) {
      int flat = tid + rep * 256;
      int kk = flat >> 5;
      int c = flat & 31;
      float4 v4 = *(const float4*)(Kp + (size_t)(kt + kk) * D_ + 4 * c);
      unsigned short h0 = f2bf(v4.x), h1 = f2bf(v4.y), h2 = f2bf(v4.z), h3 = f2bf(v4.w);
      ushort4 hi = {h0, h1, h2, h3};
      ushort4 lo = {f2bf(v4.x - bf2f(h0)), f2bf(v4.y - bf2f(h1)),
                    f2bf(v4.z - bf2f(h2)), f2bf(v4.w - bf2f(h3))};
      int idx = kk * 128 + ((4 * c) ^ (8 * (kk & 7)));
      *(ushort4*)&sKhi[idx] = hi;
      *(ushort4*)&sKlo[idx] = lo;
    }
#pragma unroll
    for (int rep = 0; rep < 2; ++rep) {
      int c = tid & 31;
      int rb = (tid >> 5) + 8 * rep;
      int kk0 = 4 * rb;
      int ks = kk0 >> 5;
      int gg = (kk0 >> 3) & 3;
      int s4 = kk0 & 7;
      const float* vbase = Vp + (size_t)(kt + kk0) * D_ + 4 * c;
      float av[4][4];
      *(float4*)av[0] = *(const float4*)(vbase);
      *(float4*)av[1] = *(const float4*)(vbase + D_);
      *(float4*)av[2] = *(const float4*)(vbase + 2 * D_);
      *(float4*)av[3] = *(const float4*)(vbase + 3 * D_);
      int dt = c >> 2;
#pragma unroll
      for (int i = 0; i < 4; ++i) {
        int d = 4 * c + i;
        int ll = 16 * gg + (d & 15);
        ushort4 wv = {f2bf(av[0][i]), f2bf(av[1][i]), f2bf(av[2][i]), f2bf(av[3][i])};
        *(ushort4*)&sV[((ks * 8 + dt) * 64 + (ll ^ (dt & 7))) * 8 + s4] = wv;
      }
    }
    __syncthreads();

    f32x4 sfr[4];
#pragma unroll
    for (int ct = 0; ct < 4; ++ct) {
      f32x4 acc = {0.f, 0.f, 0.f, 0.f};
      int kcol = ct * 16 + l15;
      int rbse = kcol * 128;
      int sw = 8 * (kcol & 7);
#pragma unroll
      for (int ds = 0; ds < 4; ++ds) {
        int off = rbse + ((32 * ds + 8 * g) ^ sw);
        bf16x8 kh = *(const bf16x8*)&sKhi[off];
        bf16x8 kl = *(const bf16x8*)&sKlo[off];
        acc = mfma_bf(qhi[ds], kh, acc);
        acc = mfma_bf(qhi[ds], kl, acc);
        acc = mfma_bf(qlo[ds], kh, acc);
      }
      sfr[ct] = acc;
    }

    float alpha[4];
#pragma unroll
    for (int r = 0; r < 4; ++r) {
      float v = fmaxf(fmaxf(sfr[0][r], sfr[1][r]), fmaxf(sfr[2][r], sfr[3][r]));
      v = fmaxf(v, __shfl_xor(v, 1));
      v = fmaxf(v, __shfl_xor(v, 2));
      v = fmaxf(v, __shfl_xor(v, 4));
      v = fmaxf(v, __shfl_xor(v, 8));
      float nm = fmaxf(mrun[r], v);
      alpha[r] = __expf(mrun[r] - nm);
      mrun[r] = nm;
      lrun[r] *= alpha[r];
    }
#pragma unroll
    for (int dt = 0; dt < 8; ++dt) {
#pragma unroll
      for (int r = 0; r < 4; ++r) accO[dt][r] *= alpha[r];
    }

    float psum[4] = {0.f, 0.f, 0.f, 0.f};
    bf16x8 pa0, pa1;
#pragma unroll
    for (int half = 0; half < 2; ++half) {
#pragma unroll
      for (int ct2 = 0; ct2 < 2; ++ct2) {
        int ct = half * 2 + ct2;
        uint32_t kglob = (uint32_t)(kt + ct * 16 + l15);
#pragma unroll
        for (int r = 0; r < 4; ++r) {
          float p = __expf(sfr[ct][r] - mrun[r]);
          psum[r] += p;
          uint32_t bits = threefry_bits(rowbase[r] + kglob);
          float pd = (bits < KEEP_THR) ? p : 0.0f;
          sPw[(g * 4 + r) * PSTRIDE + ct2 * 16 + l15] = f2bf(pd);
        }
      }
      asm volatile("s_waitcnt lgkmcnt(0)" ::: "memory");
      __builtin_amdgcn_sched_barrier(0);
      if (half == 0) pa0 = *(const bf16x8*)&sPw[l15 * PSTRIDE + 8 * g];
      else           pa1 = *(const bf16x8*)&sPw[l15 * PSTRIDE + 8 * g];
      asm volatile("s_waitcnt lgkmcnt(0)" ::: "memory");
      __builtin_amdgcn_sched_barrier(0);
    }
#pragma unroll
    for (int r = 0; r < 4; ++r) {
      float v = psum[r];
      v += __shfl_xor(v, 1);
      v += __shfl_xor(v, 2);
      v += __shfl_xor(v, 4);
      v += __shfl_xor(v, 8);
      lrun[r] += v;
    }

#pragma unroll
    for (int dt = 0; dt < 8; ++dt) {
      bf16x8 vb0 = *(const bf16x8*)&sV[((0 * 8 + dt) * 64 + (lane ^ (dt & 7))) * 8];
      accO[dt] = mfma_bf(pa0, vb0, accO[dt]);
      bf16x8 vb1 = *(const bf16x8*)&sV[((1 * 8 + dt) * 64 + (lane ^ (dt & 7))) * 8];
      accO[dt] = mfma_bf(pa1, vb1, accO[dt]);
    }
  }

#pragma unroll
  for (int r = 0; r < 4; ++r) {
    float inv = 1.0f / (0.9f * lrun[r]);
    float* orow = Op + (size_t)(q0w + g * 4 + r) * D_ + l15;
#pragma unroll
    for (int dt = 0; dt < 8; ++dt) orow[dt * 16] = accO[dt][r] * inv;
  }
}

extern "C" void kernel_launch(void* const* d_in, const int* in_sizes, int n_in,
                              void* d_out, int out_size, void* d_ws, size_t ws_size,
                              hipStream_t stream) {
  (void)in_sizes; (void)n_in; (void)out_size;
  const float* Q = (const float*)d_in[0];
  const float* K = (const float*)d_in[1];
  const float* V = (const float*)d_in[2];
  float* O = (float*)d_out;

  if (ws_size >= (size_t)3 * BUF_BYTES) {
    unsigned short* pKhi = (unsigned short*)d_ws;
    unsigned short* pKlo = (unsigned short*)((char*)d_ws + BUF_BYTES);
    unsigned short* pVf = (unsigned short*)((char*)d_ws + 2 * (size_t)BUF_BYTES);
    prepack_kernel<<<dim3(1024), dim3(256), 0, stream>>>(K, V, pKhi, pKlo, pVf);
    fattn_packed<<<dim3(512), dim3(512), 0, stream>>>(Q, pKhi, pKlo, pVf, O);
  } else {
    fattn_fallback<<<dim3(1024), dim3(256), 0, stream>>>(Q, K, V, O);
  }
}